// Round 1
// baseline (74.136 us; speedup 1.0000x reference)
//
#include <hip/hip_runtime.h>
#include <math.h>

// Problem constants (fixed by setup_inputs)
namespace {
constexpr int B_ = 32, C_ = 256, H_ = 32, W_ = 128, A_ = 64;
constexpr int AA = A_ * A_;   // 4096 positions per batch
constexpr int HW = H_ * W_;   // 4096 floats per (b,c) image = 16 KB
constexpr float MPP = 1.6f;   // 0.2 * 512 / 64
constexpr float PI_F = 3.14159265358979323846f;
}

struct Pmat {
    float p00, p01, p02, p03;
    float p10, p11, p12, p13;
    float p20, p21, p22, p23;
};

__device__ __forceinline__ Pmat make_P(int b,
                                       const float* __restrict__ shift_u,
                                       const float* __restrict__ shift_v,
                                       const float* __restrict__ heading,
                                       const float* __restrict__ camk) {
    float su = 20.f * shift_u[b];
    float sv = 20.f * shift_v[b];
    float h  = heading[b] * (10.f / 180.f) * PI_F;
    // R built from cos(-h), sin(-h)
    float ch = cosf(h);
    float sh = -sinf(h);

    const float* K = camk + b * 9;
    // rows 0,1 scaled by W/ORI_W = H/ORI_H = 0.125
    float k00 = K[0] * 0.125f, k01 = K[1] * 0.125f, k02 = K[2] * 0.125f;
    float k10 = K[3] * 0.125f, k11 = K[4] * 0.125f, k12 = K[5] * 0.125f;
    float k20 = K[6],          k21 = K[7],          k22 = K[8];

    Pmat P;
    // R columns: c0=[ch,0,sh], c1=[0,1,0], c2=[-sh,0,ch]; T=[sv,1.65,-su]
    P.p00 = k00 * ch + k02 * sh;  P.p01 = k01;
    P.p02 = -k00 * sh + k02 * ch; P.p03 = k00 * sv + k01 * 1.65f - k02 * su;
    P.p10 = k10 * ch + k12 * sh;  P.p11 = k11;
    P.p12 = -k10 * sh + k12 * ch; P.p13 = k10 * sv + k11 * 1.65f - k12 * su;
    P.p20 = k20 * ch + k22 * sh;  P.p21 = k21;
    P.p22 = -k20 * sh + k22 * ch; P.p23 = k20 * sv + k21 * 1.65f - k22 * su;
    return P;
}

__device__ __forceinline__ float4 uv_at(const Pmat& P, int pos, float Y) {
    int i = pos >> 6, j = pos & 63;
    float X = MPP * (float)(i - 32);
    float Z = MPP * (float)(j - 32);

    float u1 = P.p00 * X + P.p02 * Z + P.p03;
    float v1 = P.p10 * X + P.p12 * Z + P.p13;
    float w1 = P.p20 * X + P.p22 * Z + P.p23;

    float d0 = fmaxf(w1, 1e-6f);
    float u0 = u1 / d0, v0 = v1 / d0;

    float u1h = u1 + P.p01 * Y;
    float v1h = v1 + P.p11 * Y;
    float w1h = w1 + P.p21 * Y;
    float dh = fmaxf(w1h, 1e-6f);
    float uh = u1h / dh, vh = v1h / dh;

    return make_float4(u0, v0, uh, vh);
}

// Kernel 1: per (b,i,j) compute both UV pairs -> workspace [B*AA] float4
__global__ __launch_bounds__(256) void uv_kernel(
        const float* __restrict__ ph,
        const float* __restrict__ shift_u,
        const float* __restrict__ shift_v,
        const float* __restrict__ heading,
        const float* __restrict__ camk,
        float4* __restrict__ uvout) {
    int gid = blockIdx.x * 256 + threadIdx.x;
    if (gid >= B_ * AA) return;
    int b = gid >> 12;
    int pos = gid & (AA - 1);
    Pmat P = make_P(b, shift_u, shift_v, heading, camk);
    float Y = -ph[gid];
    uvout[gid] = uv_at(P, pos, Y);
}

__device__ __forceinline__ float bilin(const float* __restrict__ img, float ix, float iy) {
    // reference: valid = in-bounds on unclamped coords; zero outside.
    bool valid = (ix >= 0.f) && (ix <= (float)(W_ - 1)) &&
                 (iy >= 0.f) && (iy <= (float)(H_ - 1));
    if (!valid) return 0.f;
    float x0f = floorf(ix), y0f = floorf(iy);
    float fx = ix - x0f, fy = iy - y0f;
    int x0 = (int)x0f, y0 = (int)y0f;
    int x1 = min(x0 + 1, W_ - 1), y1 = min(y0 + 1, H_ - 1);
    const float* r0 = img + y0 * W_;
    const float* r1 = img + y1 * W_;
    float v00 = r0[x0], v01 = r0[x1];
    float v10 = r1[x0], v11 = r1[x1];
    float top = v00 + fx * (v01 - v00);
    float bot = v10 + fx * (v11 - v10);
    return top + fy * (bot - top);
}

// Kernel 2: one block per (b,c). Stage grd_f[b,c] (16 KB) in LDS, produce 4096 outputs.
template <bool PRECOMP>
__global__ __launch_bounds__(256) void proj_kernel(
        const float* __restrict__ grd,
        const float4* __restrict__ uv,   // PRECOMP path
        const float* __restrict__ sat,
        float* __restrict__ out,
        const float* __restrict__ ph,    // inline path
        const float* __restrict__ shift_u,
        const float* __restrict__ shift_v,
        const float* __restrict__ heading,
        const float* __restrict__ camk) {
    __shared__ float img[HW];
    int c = blockIdx.x, b = blockIdx.y;
    int tid = threadIdx.x;

    const float4* gsrc = (const float4*)(grd + ((size_t)b * C_ + c) * HW);
    float4* dimg = (float4*)img;
#pragma unroll
    for (int k = 0; k < HW / 4 / 256; ++k)
        dimg[k * 256 + tid] = gsrc[k * 256 + tid];
    __syncthreads();

    Pmat P;
    if (!PRECOMP) P = make_P(b, shift_u, shift_v, heading, camk);

    const float4* uvb = uv + (size_t)b * AA;
    const float* phb = ph + (size_t)b * AA;
    const float* satc = sat + (size_t)c * AA;
    float* outp = out + ((size_t)b * C_ + c) * AA;

#pragma unroll 4
    for (int p = 0; p < AA / 256; ++p) {
        int pos = p * 256 + tid;
        float4 q;
        if (PRECOMP) {
            q = uvb[pos];
        } else {
            q = uv_at(P, pos, -phb[pos]);
        }
        float g0 = bilin(img, q.x, q.y);
        float gh = bilin(img, q.z, q.w);
        float s = satc[pos];
        outp[pos] = gh * s + g0 * (1.f - s);
    }
}

extern "C" void kernel_launch(void* const* d_in, const int* in_sizes, int n_in,
                              void* d_out, int out_size, void* d_ws, size_t ws_size,
                              hipStream_t stream) {
    (void)in_sizes; (void)n_in; (void)out_size;
    const float* grd  = (const float*)d_in[0];   // [B,C,H,W]
    const float* ph   = (const float*)d_in[1];   // [B,1,A,A]
    const float* s_u  = (const float*)d_in[2];   // [B,1]
    const float* s_v  = (const float*)d_in[3];   // [B,1]
    const float* hd   = (const float*)d_in[4];   // [B,1]
    const float* ck   = (const float*)d_in[5];   // [B,3,3]
    const float* sat  = (const float*)d_in[6];   // [1,C,A,A]
    float* out = (float*)d_out;

    const size_t uv_bytes = (size_t)B_ * AA * sizeof(float4); // 2 MiB
    if (ws_size >= uv_bytes) {
        float4* uvws = (float4*)d_ws;
        uv_kernel<<<(B_ * AA + 255) / 256, 256, 0, stream>>>(ph, s_u, s_v, hd, ck, uvws);
        proj_kernel<true><<<dim3(C_, B_), 256, 0, stream>>>(
            grd, uvws, sat, out, nullptr, nullptr, nullptr, nullptr, nullptr);
    } else {
        proj_kernel<false><<<dim3(C_, B_), 256, 0, stream>>>(
            grd, nullptr, sat, out, ph, s_u, s_v, hd, ck);
    }
}